// Round 2
// baseline (209.454 us; speedup 1.0000x reference)
//
#include <hip/hip_runtime.h>
#include <hip/hip_bf16.h>
#include <math.h>

#define B 2
#define N 1024
#define D 128
#define DA 32
#define NH 4
#define AH 32
#define DEC_H 256
#define DEC_O 128
#define C_DIM ((NH + 1) * D)   // 640
#define TI 32
#define TJ 32

// ---------------- kernel 1: k, q, v projections ----------------
// grid B*N/8 blocks x 128 threads; 8 rows per block.
// v is written directly into cBuf columns [0,128).
__global__ __launch_bounds__(128) void qkv_kernel(
    const float* __restrict__ x,
    const float* __restrict__ Wk, const float* __restrict__ bk,
    const float* __restrict__ Wq, const float* __restrict__ bq,
    const float* __restrict__ Wv, const float* __restrict__ bv,
    float* __restrict__ kOut, float* __restrict__ qOut, float* __restrict__ cBuf)
{
    const int t = threadIdx.x;          // 0..127 = output column
    const int row0 = blockIdx.x * 8;
    __shared__ float xs[8][D];
    #pragma unroll
    for (int m = 0; m < 8; ++m) xs[m][t] = x[(size_t)(row0 + m) * D + t];
    __syncthreads();

    float ak[8], aq[8], av[8];
    const float bkv = bk[t], bqv = bq[t], bvv = bv[t];
    #pragma unroll
    for (int m = 0; m < 8; ++m) { ak[m] = bkv; aq[m] = bqv; av[m] = bvv; }

    for (int d = 0; d < D; ++d) {
        const float wk = Wk[d * D + t];
        const float wq = Wq[d * D + t];
        const float wv = Wv[d * D + t];
        #pragma unroll
        for (int m = 0; m < 8; ++m) {
            const float xv = xs[m][d];
            ak[m] = fmaf(xv, wk, ak[m]);
            aq[m] = fmaf(xv, wq, aq[m]);
            av[m] = fmaf(xv, wv, av[m]);
        }
    }
    #pragma unroll
    for (int m = 0; m < 8; ++m) {
        kOut[(size_t)(row0 + m) * D + t] = ak[m];
        qOut[(size_t)(row0 + m) * D + t] = aq[m];
        cBuf[(size_t)(row0 + m) * C_DIM + t] = av[m];
    }
}

// ---------------- kernel 2: hk = ki@Wa1_k ; hq = qi@Wa1_q + ba1 ----------------
// grid B*N blocks x 256 threads. Layout: hk[((b*NH+h)*N + n)*32 + a]
__global__ __launch_bounds__(256) void hkq_kernel(
    const float* __restrict__ kIn, const float* __restrict__ qIn,
    const float* __restrict__ Wa1, const float* __restrict__ ba1,
    float* __restrict__ hkOut, float* __restrict__ hqOut)
{
    const int row = blockIdx.x;   // b*N + n
    const int t = threadIdx.x;    // 0..255
    __shared__ float ks[D], qs[D];
    if (t < D) ks[t] = kIn[(size_t)row * D + t];
    else       qs[t - D] = qIn[(size_t)row * D + (t - D)];
    __syncthreads();

    const bool isq = t >= 128;
    const int tt = t & 127;
    const int head = tt >> 5;   // 0..3
    const int a = tt & 31;      // 0..31
    const float* src = isq ? qs : ks;
    const float* W = Wa1 + (isq ? DA * AH : 0);
    float acc = isq ? ba1[a] : 0.f;
    #pragma unroll
    for (int c = 0; c < DA; ++c)
        acc = fmaf(src[head * DA + c], W[c * AH + a], acc);

    const int b = row >> 10, n = row & (N - 1);
    float* dst = isq ? hqOut : hkOut;
    dst[(((size_t)(b * NH + head)) * N + n) * 32 + a] = acc;
}

// ---------------- kernel 3: attention ----------------
// grid = B*NH*(N/TI) = 256 blocks x 256 threads. Block handles one (b,h) and a
// 32-row i-tile. Loops over 32-row j-tiles: stage hq,v in LDS; compute 32x32
// sigmoid-weights; accumulate out[i][d] += w[i][j]*v[j][d] (4i x 4d per thread).
__global__ __launch_bounds__(256) void attn_kernel(
    const float* __restrict__ hk, const float* __restrict__ hq,
    const float* __restrict__ Wa2, const float* __restrict__ ba2,
    float* __restrict__ cBuf)
{
    const int t = threadIdx.x;
    const int tile = blockIdx.x & 31;   // N/TI = 32
    const int bh = blockIdx.x >> 5;     // b*NH + h
    const int b = bh >> 2, h = bh & 3;
    const int i0 = tile * TI;

    __shared__ float hks[TI][36];
    __shared__ float hqs[TJ][36];
    __shared__ float vs[TJ][D];
    __shared__ float wst[TJ][36];   // transposed: wst[j][i]
    __shared__ float wa2s[AH];

    if (t < AH) wa2s[t] = Wa2[t];
    const float ba2v = ba2[0];

    {   // load hk tile (32x32)
        const float* src = hk + ((size_t)bh * N + i0) * 32;
        for (int idx = t; idx < TI * 32; idx += 256)
            hks[idx >> 5][idx & 31] = src[idx];
    }

    const int iq = t >> 5;               // 0..7  : i block = iq*4 + 0..3
    const int dq = t & 31;               // 0..31 : d block = dq*4 + 0..3
    const int ti2 = (t >> 4) << 1;       // score rows: ti2, ti2+1
    const int tj2 = (t & 15) << 1;       // score cols: tj2, tj2+1

    float4 acc[4];
    #pragma unroll
    for (int m = 0; m < 4; ++m) acc[m] = make_float4(0.f, 0.f, 0.f, 0.f);

    for (int j0 = 0; j0 < N; j0 += TJ) {
        __syncthreads();   // protect hqs/vs/wst from previous iteration readers
        {   // load hq tile
            const float* src = hq + ((size_t)bh * N + j0) * 32;
            for (int idx = t; idx < TJ * 32; idx += 256)
                hqs[idx >> 5][idx & 31] = src[idx];
        }
        {   // load v tile from cBuf cols [0,128)
            const float4* src = reinterpret_cast<const float4*>(cBuf + (size_t)(b * N + j0) * C_DIM);
            for (int idx = t; idx < TJ * 32; idx += 256) {
                const int jr = idx >> 5, dc = idx & 31;
                reinterpret_cast<float4*>(&vs[jr][0])[dc] = src[(size_t)jr * (C_DIM / 4) + dc];
            }
        }
        __syncthreads();

        {   // scores: 2x2 per thread
            float s00 = ba2v, s01 = ba2v, s10 = ba2v, s11 = ba2v;
            #pragma unroll
            for (int a = 0; a < AH; a += 4) {
                const float4 k0 = *reinterpret_cast<const float4*>(&hks[ti2][a]);
                const float4 k1 = *reinterpret_cast<const float4*>(&hks[ti2 + 1][a]);
                const float4 q0 = *reinterpret_cast<const float4*>(&hqs[tj2][a]);
                const float4 q1 = *reinterpret_cast<const float4*>(&hqs[tj2 + 1][a]);
                const float4 w4 = *reinterpret_cast<const float4*>(&wa2s[a]);
                s00 += w4.x * fmaxf(k0.x + q0.x, 0.f) + w4.y * fmaxf(k0.y + q0.y, 0.f)
                     + w4.z * fmaxf(k0.z + q0.z, 0.f) + w4.w * fmaxf(k0.w + q0.w, 0.f);
                s01 += w4.x * fmaxf(k0.x + q1.x, 0.f) + w4.y * fmaxf(k0.y + q1.y, 0.f)
                     + w4.z * fmaxf(k0.z + q1.z, 0.f) + w4.w * fmaxf(k0.w + q1.w, 0.f);
                s10 += w4.x * fmaxf(k1.x + q0.x, 0.f) + w4.y * fmaxf(k1.y + q0.y, 0.f)
                     + w4.z * fmaxf(k1.z + q0.z, 0.f) + w4.w * fmaxf(k1.w + q0.w, 0.f);
                s11 += w4.x * fmaxf(k1.x + q1.x, 0.f) + w4.y * fmaxf(k1.y + q1.y, 0.f)
                     + w4.z * fmaxf(k1.z + q1.z, 0.f) + w4.w * fmaxf(k1.w + q1.w, 0.f);
            }
            const int gi0 = i0 + ti2, gj0 = j0 + tj2;
            if (gi0 == gj0)     { s00 -= 10000.f; s11 -= 10000.f; }
            if (gi0 == gj0 + 1) { s01 -= 10000.f; }
            if (gi0 + 1 == gj0) { s10 -= 10000.f; }
            wst[tj2][ti2]         = 1.f / (1.f + __expf(-s00));
            wst[tj2 + 1][ti2]     = 1.f / (1.f + __expf(-s01));
            wst[tj2][ti2 + 1]     = 1.f / (1.f + __expf(-s10));
            wst[tj2 + 1][ti2 + 1] = 1.f / (1.f + __expf(-s11));
        }
        __syncthreads();

        // accumulate
        #pragma unroll 8
        for (int j = 0; j < TJ; ++j) {
            const float4 wv = *reinterpret_cast<const float4*>(&wst[j][iq * 4]);
            const float4 v4 = *reinterpret_cast<const float4*>(&vs[j][dq * 4]);
            acc[0].x = fmaf(wv.x, v4.x, acc[0].x); acc[0].y = fmaf(wv.x, v4.y, acc[0].y);
            acc[0].z = fmaf(wv.x, v4.z, acc[0].z); acc[0].w = fmaf(wv.x, v4.w, acc[0].w);
            acc[1].x = fmaf(wv.y, v4.x, acc[1].x); acc[1].y = fmaf(wv.y, v4.y, acc[1].y);
            acc[1].z = fmaf(wv.y, v4.z, acc[1].z); acc[1].w = fmaf(wv.y, v4.w, acc[1].w);
            acc[2].x = fmaf(wv.z, v4.x, acc[2].x); acc[2].y = fmaf(wv.z, v4.y, acc[2].y);
            acc[2].z = fmaf(wv.z, v4.z, acc[2].z); acc[2].w = fmaf(wv.z, v4.w, acc[2].w);
            acc[3].x = fmaf(wv.w, v4.x, acc[3].x); acc[3].y = fmaf(wv.w, v4.y, acc[3].y);
            acc[3].z = fmaf(wv.w, v4.z, acc[3].z); acc[3].w = fmaf(wv.w, v4.w, acc[3].w);
        }
    }

    // write head output into cBuf columns [(h+1)*128, (h+2)*128)
    float* dst = cBuf + ((size_t)(b * N + i0)) * C_DIM + (h + 1) * D;
    #pragma unroll
    for (int m = 0; m < 4; ++m) {
        reinterpret_cast<float4*>(dst + (size_t)(iq * 4 + m) * C_DIM)[dq] = acc[m];
    }
}

// ---------------- kernel 4: decoder ----------------
// grid B*N/8 blocks x 256 threads; 8 rows per block.
__global__ __launch_bounds__(256) void dec_kernel(
    const float* __restrict__ cBuf,
    const float* __restrict__ Wd1, const float* __restrict__ bd1,
    const float* __restrict__ Wd2, const float* __restrict__ bd2,
    float* __restrict__ out)
{
    const int t = threadIdx.x;       // 0..255
    const int r0 = blockIdx.x * 8;
    __shared__ float cs[8][C_DIM];
    __shared__ float hs[8][DEC_H];

    {   // load 8 rows of c (8*640 floats = 1280 float4)
        const float4* src = reinterpret_cast<const float4*>(cBuf + (size_t)r0 * C_DIM);
        float4* dst4 = reinterpret_cast<float4*>(&cs[0][0]);
        for (int idx = t; idx < 8 * C_DIM / 4; idx += 256) dst4[idx] = src[idx];
    }
    __syncthreads();

    float hacc[8];
    const float b1 = bd1[t];
    #pragma unroll
    for (int m = 0; m < 8; ++m) hacc[m] = b1;
    for (int d = 0; d < C_DIM; ++d) {
        const float w = Wd1[(size_t)d * DEC_H + t];
        #pragma unroll
        for (int m = 0; m < 8; ++m) hacc[m] = fmaf(cs[m][d], w, hacc[m]);
    }
    #pragma unroll
    for (int m = 0; m < 8; ++m) hs[m][t] = fmaxf(hacc[m], 0.f);
    __syncthreads();

    // second layer: 8 rows x 128 cols; thread handles rows {rb, rb+2, rb+4, rb+6}, col o
    const int o = t & 127, rb = t >> 7;
    float oacc[4];
    #pragma unroll
    for (int m = 0; m < 4; ++m) oacc[m] = bd2[o];
    for (int hh = 0; hh < DEC_H; ++hh) {
        const float w = Wd2[(size_t)hh * DEC_O + o];
        #pragma unroll
        for (int m = 0; m < 4; ++m) oacc[m] = fmaf(hs[rb + 2 * m][hh], w, oacc[m]);
    }
    #pragma unroll
    for (int m = 0; m < 4; ++m)
        out[(size_t)(r0 + rb + 2 * m) * DEC_O + o] = oacc[m];
}

extern "C" void kernel_launch(void* const* d_in, const int* in_sizes, int n_in,
                              void* d_out, int out_size, void* d_ws, size_t ws_size,
                              hipStream_t stream)
{
    const float* x   = (const float*)d_in[0];
    const float* Wk  = (const float*)d_in[1];
    const float* bk  = (const float*)d_in[2];
    const float* Wq  = (const float*)d_in[3];
    const float* bq  = (const float*)d_in[4];
    const float* Wv  = (const float*)d_in[5];
    const float* bv  = (const float*)d_in[6];
    const float* Wa1 = (const float*)d_in[7];
    const float* ba1 = (const float*)d_in[8];
    const float* Wa2 = (const float*)d_in[9];
    const float* ba2 = (const float*)d_in[10];
    const float* Wd1 = (const float*)d_in[11];
    const float* bd1 = (const float*)d_in[12];
    const float* Wd2 = (const float*)d_in[13];
    const float* bd2 = (const float*)d_in[14];
    float* out = (float*)d_out;

    float* ws = (float*)d_ws;
    float* kBuf  = ws;                       // B*N*D
    float* qBuf  = kBuf + (size_t)B * N * D; // B*N*D
    float* hkBuf = qBuf + (size_t)B * N * D; // B*NH*N*32
    float* hqBuf = hkBuf + (size_t)B * NH * N * 32;
    float* cBuf  = hqBuf + (size_t)B * NH * N * 32; // B*N*C_DIM

    qkv_kernel<<<B * N / 8, 128, 0, stream>>>(x, Wk, bk, Wq, bq, Wv, bv, kBuf, qBuf, cBuf);
    hkq_kernel<<<B * N, 256, 0, stream>>>(kBuf, qBuf, Wa1, ba1, hkBuf, hqBuf);
    attn_kernel<<<B * NH * (N / TI), 256, 0, stream>>>(hkBuf, hqBuf, Wa2, ba2, cBuf);
    dec_kernel<<<B * N / 8, 256, 0, stream>>>(cBuf, Wd1, bd1, Wd2, bd2, out);
}

// Round 3
// 122.211 us; speedup vs baseline: 1.7139x; 1.7139x over previous
//
#include <hip/hip_runtime.h>
#include <hip/hip_bf16.h>
#include <math.h>

#define B 2
#define N 1024
#define D 128
#define DA 32
#define NH 4
#define AH 32
#define DEC_H 256
#define DEC_O 128
#define C_DIM ((NH + 1) * D)   // 640
#define TI 32
#define TJ 32
#define SPLIT 4                // j-dimension split for occupancy
#define JCHUNK (N / SPLIT)     // 256

// ---------------- kernel 1: k, q, v projections ----------------
// grid B*N/4 = 512 blocks x 384 threads; 4 rows per block.
// thread t: matrix mat = t>>7 (0=k,1=q,2=v), output column t&127.
// v is written directly into cBuf columns [0,128).
__global__ __launch_bounds__(384) void qkv_kernel(
    const float* __restrict__ x,
    const float* __restrict__ Wk, const float* __restrict__ bk,
    const float* __restrict__ Wq, const float* __restrict__ bq,
    const float* __restrict__ Wv, const float* __restrict__ bv,
    float* __restrict__ kOut, float* __restrict__ qOut, float* __restrict__ cBuf)
{
    const int t = threadIdx.x;
    const int row0 = blockIdx.x * 4;
    __shared__ float xs[4][D];
    for (int idx = t; idx < 4 * D; idx += 384)
        xs[idx >> 7][idx & 127] = x[(size_t)row0 * D + idx];
    __syncthreads();

    const int mat = t >> 7;      // 0,1,2 (wave-uniform: 128 | 64)
    const int col = t & 127;
    const float* W = (mat == 0) ? Wk : (mat == 1) ? Wq : Wv;
    const float bias = (mat == 0) ? bk[col] : (mat == 1) ? bq[col] : bv[col];

    float a[4];
    #pragma unroll
    for (int m = 0; m < 4; ++m) a[m] = bias;
    for (int d = 0; d < D; ++d) {
        const float w = W[d * D + col];
        #pragma unroll
        for (int m = 0; m < 4; ++m) a[m] = fmaf(xs[m][d], w, a[m]);
    }
    if (mat == 0) {
        #pragma unroll
        for (int m = 0; m < 4; ++m) kOut[(size_t)(row0 + m) * D + col] = a[m];
    } else if (mat == 1) {
        #pragma unroll
        for (int m = 0; m < 4; ++m) qOut[(size_t)(row0 + m) * D + col] = a[m];
    } else {
        #pragma unroll
        for (int m = 0; m < 4; ++m) cBuf[(size_t)(row0 + m) * C_DIM + col] = a[m];
    }
}

// ---------------- kernel 2: hk = ki@Wa1_k ; hq = qi@Wa1_q + ba1 ----------------
// grid B*N blocks x 256 threads. Layout: hk[((b*NH+h)*N + n)*32 + a]
__global__ __launch_bounds__(256) void hkq_kernel(
    const float* __restrict__ kIn, const float* __restrict__ qIn,
    const float* __restrict__ Wa1, const float* __restrict__ ba1,
    float* __restrict__ hkOut, float* __restrict__ hqOut)
{
    const int row = blockIdx.x;   // b*N + n
    const int t = threadIdx.x;    // 0..255
    __shared__ float ks[D], qs[D];
    if (t < D) ks[t] = kIn[(size_t)row * D + t];
    else       qs[t - D] = qIn[(size_t)row * D + (t - D)];
    __syncthreads();

    const bool isq = t >= 128;
    const int tt = t & 127;
    const int head = tt >> 5;   // 0..3
    const int a = tt & 31;      // 0..31
    const float* src = isq ? qs : ks;
    const float* W = Wa1 + (isq ? DA * AH : 0);
    float acc = isq ? ba1[a] : 0.f;
    #pragma unroll
    for (int c = 0; c < DA; ++c)
        acc = fmaf(src[head * DA + c], W[c * AH + a], acc);

    const int b = row >> 10, n = row & (N - 1);
    float* dst = isq ? hqOut : hkOut;
    dst[(((size_t)(b * NH + head)) * N + n) * 32 + a] = acc;
}

// ---------------- kernel 3: attention (j-split partials) ----------------
// grid = B*NH*(N/TI)*SPLIT = 1024 blocks x 256 threads.
// blockIdx.x = ((bh*32 + tile)*SPLIT + sc). Block handles (b,h), a 32-row
// i-tile, and j in [sc*JCHUNK, (sc+1)*JCHUNK). Writes 32x128 partial to pBuf.
__global__ __launch_bounds__(256) void attn_kernel(
    const float* __restrict__ hk, const float* __restrict__ hq,
    const float* __restrict__ Wa2, const float* __restrict__ ba2,
    const float* __restrict__ cBuf, float* __restrict__ pBuf)
{
    const int t = threadIdx.x;
    const int sc = blockIdx.x & (SPLIT - 1);
    const int tile = (blockIdx.x >> 2) & 31;
    const int bh = blockIdx.x >> 7;     // b*NH + h
    const int b = bh >> 2;
    const int i0 = tile * TI;

    __shared__ float hks[TI][36];
    __shared__ float hqs[TJ][36];
    __shared__ float vs[TJ][D];
    __shared__ float wst[TJ][36];   // transposed: wst[j][i]
    __shared__ float wa2s[AH];

    if (t < AH) wa2s[t] = Wa2[t];
    const float ba2v = ba2[0];

    {   // load hk tile (32x32)
        const float* src = hk + ((size_t)bh * N + i0) * 32;
        for (int idx = t; idx < TI * 32; idx += 256)
            hks[idx >> 5][idx & 31] = src[idx];
    }

    const int iq = t >> 5;               // 0..7  : i block = iq*4 + 0..3
    const int dq = t & 31;               // 0..31 : d block = dq*4 + 0..3
    const int ti2 = (t >> 4) << 1;       // score rows: ti2, ti2+1
    const int tj2 = (t & 15) << 1;       // score cols: tj2, tj2+1

    float4 acc[4];
    #pragma unroll
    for (int m = 0; m < 4; ++m) acc[m] = make_float4(0.f, 0.f, 0.f, 0.f);

    const int jbeg = sc * JCHUNK, jend = jbeg + JCHUNK;
    for (int j0 = jbeg; j0 < jend; j0 += TJ) {
        __syncthreads();   // protect hqs/vs/wst from previous iteration readers
        {   // load hq tile
            const float* src = hq + ((size_t)bh * N + j0) * 32;
            for (int idx = t; idx < TJ * 32; idx += 256)
                hqs[idx >> 5][idx & 31] = src[idx];
        }
        {   // load v tile from cBuf cols [0,128)
            const float4* src = reinterpret_cast<const float4*>(cBuf + (size_t)(b * N + j0) * C_DIM);
            for (int idx = t; idx < TJ * 32; idx += 256) {
                const int jr = idx >> 5, dc = idx & 31;
                reinterpret_cast<float4*>(&vs[jr][0])[dc] = src[(size_t)jr * (C_DIM / 4) + dc];
            }
        }
        __syncthreads();

        {   // scores: 2x2 per thread
            float s00 = ba2v, s01 = ba2v, s10 = ba2v, s11 = ba2v;
            #pragma unroll
            for (int a = 0; a < AH; a += 4) {
                const float4 k0 = *reinterpret_cast<const float4*>(&hks[ti2][a]);
                const float4 k1 = *reinterpret_cast<const float4*>(&hks[ti2 + 1][a]);
                const float4 q0 = *reinterpret_cast<const float4*>(&hqs[tj2][a]);
                const float4 q1 = *reinterpret_cast<const float4*>(&hqs[tj2 + 1][a]);
                const float4 w4 = *reinterpret_cast<const float4*>(&wa2s[a]);
                s00 += w4.x * fmaxf(k0.x + q0.x, 0.f) + w4.y * fmaxf(k0.y + q0.y, 0.f)
                     + w4.z * fmaxf(k0.z + q0.z, 0.f) + w4.w * fmaxf(k0.w + q0.w, 0.f);
                s01 += w4.x * fmaxf(k0.x + q1.x, 0.f) + w4.y * fmaxf(k0.y + q1.y, 0.f)
                     + w4.z * fmaxf(k0.z + q1.z, 0.f) + w4.w * fmaxf(k0.w + q1.w, 0.f);
                s10 += w4.x * fmaxf(k1.x + q0.x, 0.f) + w4.y * fmaxf(k1.y + q0.y, 0.f)
                     + w4.z * fmaxf(k1.z + q0.z, 0.f) + w4.w * fmaxf(k1.w + q0.w, 0.f);
                s11 += w4.x * fmaxf(k1.x + q1.x, 0.f) + w4.y * fmaxf(k1.y + q1.y, 0.f)
                     + w4.z * fmaxf(k1.z + q1.z, 0.f) + w4.w * fmaxf(k1.w + q1.w, 0.f);
            }
            const int gi0 = i0 + ti2, gj0 = j0 + tj2;
            if (gi0 == gj0)     { s00 -= 10000.f; s11 -= 10000.f; }
            if (gi0 == gj0 + 1) { s01 -= 10000.f; }
            if (gi0 + 1 == gj0) { s10 -= 10000.f; }
            wst[tj2][ti2]         = 1.f / (1.f + __expf(-s00));
            wst[tj2 + 1][ti2]     = 1.f / (1.f + __expf(-s01));
            wst[tj2][ti2 + 1]     = 1.f / (1.f + __expf(-s10));
            wst[tj2 + 1][ti2 + 1] = 1.f / (1.f + __expf(-s11));
        }
        __syncthreads();

        // accumulate out[i][d] += w[i][j] * v[j][d]   (4i x 4d per thread)
        #pragma unroll 8
        for (int j = 0; j < TJ; ++j) {
            const float4 wv = *reinterpret_cast<const float4*>(&wst[j][iq * 4]);
            const float4 v4 = *reinterpret_cast<const float4*>(&vs[j][dq * 4]);
            acc[0].x = fmaf(wv.x, v4.x, acc[0].x); acc[0].y = fmaf(wv.x, v4.y, acc[0].y);
            acc[0].z = fmaf(wv.x, v4.z, acc[0].z); acc[0].w = fmaf(wv.x, v4.w, acc[0].w);
            acc[1].x = fmaf(wv.y, v4.x, acc[1].x); acc[1].y = fmaf(wv.y, v4.y, acc[1].y);
            acc[1].z = fmaf(wv.y, v4.z, acc[1].z); acc[1].w = fmaf(wv.y, v4.w, acc[1].w);
            acc[2].x = fmaf(wv.z, v4.x, acc[2].x); acc[2].y = fmaf(wv.z, v4.y, acc[2].y);
            acc[2].z = fmaf(wv.z, v4.z, acc[2].z); acc[2].w = fmaf(wv.z, v4.w, acc[2].w);
            acc[3].x = fmaf(wv.w, v4.x, acc[3].x); acc[3].y = fmaf(wv.w, v4.y, acc[3].y);
            acc[3].z = fmaf(wv.w, v4.z, acc[3].z); acc[3].w = fmaf(wv.w, v4.w, acc[3].w);
        }
    }

    // write 32x128 partial tile to pBuf[blockIdx.x]
    float* dst = pBuf + (size_t)blockIdx.x * (TI * D);
    #pragma unroll
    for (int m = 0; m < 4; ++m)
        reinterpret_cast<float4*>(dst + (size_t)(iq * 4 + m) * D)[dq] = acc[m];
}

// ---------------- kernel 3b: reduce SPLIT partials into cBuf ----------------
// 1024 blocks x 256 threads; one float4 output element per thread.
__global__ __launch_bounds__(256) void reduce_kernel(
    const float* __restrict__ pBuf, float* __restrict__ cBuf)
{
    const int e4 = blockIdx.x * 256 + threadIdx.x;   // 0 .. 262143
    const int d4 = e4 & 31;
    const int i = (e4 >> 5) & 31;
    const int tile = (e4 >> 10) & 31;
    const int bh = e4 >> 15;
    const float4* p = reinterpret_cast<const float4*>(pBuf);
    const size_t base = ((size_t)(bh * 32 + tile) * SPLIT) * (TI * D / 4) + i * (D / 4) + d4;
    float4 s = p[base];
    #pragma unroll
    for (int sc = 1; sc < SPLIT; ++sc) {
        const float4 q = p[base + (size_t)sc * (TI * D / 4)];
        s.x += q.x; s.y += q.y; s.z += q.z; s.w += q.w;
    }
    const int b = bh >> 2, h = bh & 3;
    reinterpret_cast<float4*>(cBuf + (size_t)(b * N + tile * 32 + i) * C_DIM + (h + 1) * D)[d4] = s;
}

// ---------------- kernel 4: decoder ----------------
// grid B*N/8 = 256 blocks x 512 threads; 8 rows per block.
__global__ __launch_bounds__(512) void dec_kernel(
    const float* __restrict__ cBuf,
    const float* __restrict__ Wd1, const float* __restrict__ bd1,
    const float* __restrict__ Wd2, const float* __restrict__ bd2,
    float* __restrict__ out)
{
    const int t = threadIdx.x;       // 0..511
    const int r0 = blockIdx.x * 8;
    __shared__ float cs[8][C_DIM];
    __shared__ float hs[8][DEC_H];

    {   // load 8 rows of c (8*640 floats = 1280 float4)
        const float4* src = reinterpret_cast<const float4*>(cBuf + (size_t)r0 * C_DIM);
        float4* dst4 = reinterpret_cast<float4*>(&cs[0][0]);
        for (int idx = t; idx < 8 * C_DIM / 4; idx += 512) dst4[idx] = src[idx];
    }
    __syncthreads();

    // layer 1: col = t&255, rows (t>>8)*4 .. +3
    {
        const int col = t & 255, rh = t >> 8;
        float hacc[4];
        const float b1 = bd1[col];
        #pragma unroll
        for (int m = 0; m < 4; ++m) hacc[m] = b1;
        for (int d = 0; d < C_DIM; ++d) {
            const float w = Wd1[(size_t)d * DEC_H + col];
            #pragma unroll
            for (int m = 0; m < 4; ++m) hacc[m] = fmaf(cs[rh * 4 + m][d], w, hacc[m]);
        }
        #pragma unroll
        for (int m = 0; m < 4; ++m) hs[rh * 4 + m][col] = fmaxf(hacc[m], 0.f);
    }
    __syncthreads();

    // layer 2: col o = t&127, rows (t>>7)*2 .. +1
    {
        const int o = t & 127, rq = t >> 7;
        float oacc[2];
        const float b2 = bd2[o];
        #pragma unroll
        for (int m = 0; m < 2; ++m) oacc[m] = b2;
        for (int hh = 0; hh < DEC_H; ++hh) {
            const float w = Wd2[(size_t)hh * DEC_O + o];
            #pragma unroll
            for (int m = 0; m < 2; ++m) oacc[m] = fmaf(hs[rq * 2 + m][hh], w, oacc[m]);
        }
        #pragma unroll
        for (int m = 0; m < 2; ++m)
            out[(size_t)(r0 + rq * 2 + m) * DEC_O + o] = oacc[m];
    }
}

extern "C" void kernel_launch(void* const* d_in, const int* in_sizes, int n_in,
                              void* d_out, int out_size, void* d_ws, size_t ws_size,
                              hipStream_t stream)
{
    const float* x   = (const float*)d_in[0];
    const float* Wk  = (const float*)d_in[1];
    const float* bk  = (const float*)d_in[2];
    const float* Wq  = (const float*)d_in[3];
    const float* bq  = (const float*)d_in[4];
    const float* Wv  = (const float*)d_in[5];
    const float* bv  = (const float*)d_in[6];
    const float* Wa1 = (const float*)d_in[7];
    const float* ba1 = (const float*)d_in[8];
    const float* Wa2 = (const float*)d_in[9];
    const float* ba2 = (const float*)d_in[10];
    const float* Wd1 = (const float*)d_in[11];
    const float* bd1 = (const float*)d_in[12];
    const float* Wd2 = (const float*)d_in[13];
    const float* bd2 = (const float*)d_in[14];
    float* out = (float*)d_out;

    float* ws = (float*)d_ws;
    float* kBuf  = ws;                                   // B*N*D
    float* qBuf  = kBuf + (size_t)B * N * D;             // B*N*D
    float* hkBuf = qBuf + (size_t)B * N * D;             // B*NH*N*32
    float* hqBuf = hkBuf + (size_t)B * NH * N * 32;      // B*NH*N*32
    float* cBuf  = hqBuf + (size_t)B * NH * N * 32;      // B*N*C_DIM
    float* pBuf  = cBuf + (size_t)B * N * C_DIM;         // B*NH*32*SPLIT*TI*D = 4.19M floats

    qkv_kernel<<<B * N / 4, 384, 0, stream>>>(x, Wk, bk, Wq, bq, Wv, bv, kBuf, qBuf, cBuf);
    hkq_kernel<<<B * N, 256, 0, stream>>>(kBuf, qBuf, Wa1, ba1, hkBuf, hqBuf);
    attn_kernel<<<B * NH * (N / TI) * SPLIT, 256, 0, stream>>>(hkBuf, hqBuf, Wa2, ba2, cBuf, pBuf);
    reduce_kernel<<<B * NH * (N / TI) * TI * D / 4 / 256, 256, 0, stream>>>(pBuf, cBuf);
    dec_kernel<<<B * N / 8, 512, 0, stream>>>(cBuf, Wd1, bd1, Wd2, bd2, out);
}